// Round 9
// baseline (148.807 us; speedup 1.0000x reference)
//
#include <hip/hip_runtime.h>
#include <math.h>

#define CHUNK 256     // rows per chunk; SL=2048 -> 8 chunks/job, SS=512 -> 2
#define NBLK  2048    // persistent grid = exactly one full-residency round

// Persistent uniform-work kernel: grid = NBLK blocks; each block loops over
// chunks cid = bid + r*NBLK. Every chunk is identical work (256 rows), so
// the device stays at full residency from start to finish - no tail round.
// Inner loop = R4's proven 4-lane-per-row layout (2 rows/thread/iter).
__global__ __launch_bounds__(256) void cosine_chunk_kernel(
    const float* __restrict__ item,
    const float* __restrict__ seqL, const int* __restrict__ indL,
    const float* __restrict__ seqS, const int* __restrict__ indS,
    float* __restrict__ cosL, float* __restrict__ cosS,
    int* __restrict__ histG,
    int B, int SL, int SS, int nbL, int nbS,
    int nchL, int totalChunks, int rounds)
{
    const int tid = threadIdx.x;
    __shared__ float item_n[64];
    __shared__ int   hist[64];

    for (int r = 0; r < rounds; ++r) {
        const int cid = (int)blockIdx.x + r * NBLK;
        if (cid >= totalChunks) break;

        const bool isLong = cid < B * nchL;
        const int  rel    = isLong ? cid : cid - B * nchL;
        const int  nch    = isLong ? nchL : (totalChunks / B - nchL); // 8 or 2
        const int  b      = rel / nch;
        const int  chunk  = rel % nch;
        const int  S      = isLong ? SL : SS;
        const int  nb     = isLong ? nbL : nbS;
        const int  bias   = (nb - 2) / 2;        // 22 -> 10, 42 -> 20
        const float scale = (float)bias;         // exactly 1/eps
        const int  job    = isLong ? b : B + b;
        const float* __restrict__ seq = isLong ? seqL : seqS;
        const int*   __restrict__ ind = isLong ? indL : indS;
        float* __restrict__ cosOut = isLong ? cosL : cosS;

        // Phase 1 (tid<64): zero hist, normalize item row.
        if (tid < 64) {
            hist[tid] = 0;
            float v = item[(size_t)b * 64 + tid];
            float sq = v * v;
            #pragma unroll
            for (int off = 32; off >= 1; off >>= 1)
                sq += __shfl_xor(sq, off, 64);
            item_n[tid] = v * (1.0f / (sqrtf(sq) + 1e-8f));
        }
        __syncthreads();

        const int lane4 = tid & 3;               // float4 slot phase in row
        const int rowId = tid >> 2;              // 0..63
        const float4* __restrict__ item4 = reinterpret_cast<const float4*>(item_n);
        const float4 i0 = item4[0 * 4 + lane4];
        const float4 i1 = item4[1 * 4 + lane4];
        const float4 i2 = item4[2 * 4 + lane4];
        const float4 i3 = item4[3 * 4 + lane4];

        const float4* __restrict__ seqb = reinterpret_cast<const float4*>(seq) + (size_t)b * S * 16;
        const int*    __restrict__ indb = ind    + (size_t)b * S;
        float*        __restrict__ cosb = cosOut + (size_t)b * S;

        const int rowBeg = chunk * CHUNK;        // CHUNK divisible by 128

        #pragma unroll
        for (int it = 0; it < CHUNK / 128; ++it) {
            const int r0 = rowBeg + it * 128 + rowId;
            const int r1 = r0 + 64;

            int iv0 = 1, iv1 = 1;
            if (lane4 == 0) { iv0 = indb[r0]; iv1 = indb[r1]; }

            const float4* P = &seqb[(size_t)r0 * 16 + lane4];
            float4 a0 = P[0],    a1 = P[4],    a2 = P[8],    a3 = P[12];
            float4 b0 = P[1024], b1 = P[1028], b2 = P[1032], b3 = P[1036];

            float dot0 = i0.x*a0.x + i0.y*a0.y + i0.z*a0.z + i0.w*a0.w
                       + i1.x*a1.x + i1.y*a1.y + i1.z*a1.z + i1.w*a1.w
                       + i2.x*a2.x + i2.y*a2.y + i2.z*a2.z + i2.w*a2.w
                       + i3.x*a3.x + i3.y*a3.y + i3.z*a3.z + i3.w*a3.w;
            float sq0  = a0.x*a0.x + a0.y*a0.y + a0.z*a0.z + a0.w*a0.w
                       + a1.x*a1.x + a1.y*a1.y + a1.z*a1.z + a1.w*a1.w
                       + a2.x*a2.x + a2.y*a2.y + a2.z*a2.z + a2.w*a2.w
                       + a3.x*a3.x + a3.y*a3.y + a3.z*a3.z + a3.w*a3.w;
            float dot1 = i0.x*b0.x + i0.y*b0.y + i0.z*b0.z + i0.w*b0.w
                       + i1.x*b1.x + i1.y*b1.y + i1.z*b1.z + i1.w*b1.w
                       + i2.x*b2.x + i2.y*b2.y + i2.z*b2.z + i2.w*b2.w
                       + i3.x*b3.x + i3.y*b3.y + i3.z*b3.z + i3.w*b3.w;
            float sq1  = b0.x*b0.x + b0.y*b0.y + b0.z*b0.z + b0.w*b0.w
                       + b1.x*b1.x + b1.y*b1.y + b1.z*b1.z + b1.w*b1.w
                       + b2.x*b2.x + b2.y*b2.y + b2.z*b2.z + b2.w*b2.w
                       + b3.x*b3.x + b3.y*b3.y + b3.z*b3.z + b3.w*b3.w;

            #pragma unroll
            for (int off = 1; off <= 2; off <<= 1) {
                dot0 += __shfl_xor(dot0, off, 64);
                sq0  += __shfl_xor(sq0,  off, 64);
                dot1 += __shfl_xor(dot1, off, 64);
                sq1  += __shfl_xor(sq1,  off, 64);
            }

            if (lane4 == 0) {
                float cos0 = dot0 / (sqrtf(sq0) + 1e-8f);
                if (iv0 <= 0) cos0 = -2.0f;
                cosb[r0] = cos0;
                const int id0 = (int)ceilf(cos0 * scale) + bias;
                if (id0 >= 0 && id0 < nb) atomicAdd(&hist[id0], 1);

                float cos1 = dot1 / (sqrtf(sq1) + 1e-8f);
                if (iv1 <= 0) cos1 = -2.0f;
                cosb[r1] = cos1;
                const int id1 = (int)ceilf(cos1 * scale) + bias;
                if (id1 >= 0 && id1 < nb) atomicAdd(&hist[id1], 1);
            }
        }
        __syncthreads();

        // Merge block-local histogram into the global per-job histogram.
        // (Same tid<64 threads zero hist at the top of the next round, so
        // no extra barrier is needed here.)
        if (tid < 64) {
            const int c = hist[tid];
            if (c > 0) atomicAdd(&histG[(size_t)job * 64 + tid], c);
        }
    }
}

// Tiny epilogue: st[b, id*8+j] = log(count+1) * emb[id*8+j]
__global__ __launch_bounds__(64) void simtier_epilogue_kernel(
    const int* __restrict__ histG,
    const float* __restrict__ embL, const float* __restrict__ embS,
    float* __restrict__ stL, float* __restrict__ stS,
    int B, int nbL, int nbS)
{
    const int j = (int)blockIdx.x;           // 0..2B-1
    const bool isLong = j < B;
    const int b  = isLong ? j : j - B;
    const int nb = isLong ? nbL : nbS;
    const float* __restrict__ emb = isLong ? embL : embS;
    float* __restrict__ st = isLong ? stL : stS;
    const int* __restrict__ h = histG + (size_t)j * 64;

    const int nout = nb * 8;
    for (int t = threadIdx.x; t < nout; t += 64) {
        const float c = (float)h[t >> 3];
        st[(size_t)b * nout + t] = logf(c + 1.0f) * emb[t];
    }
}

extern "C" void kernel_launch(void* const* d_in, const int* in_sizes, int n_in,
                              void* d_out, int out_size, void* d_ws, size_t ws_size,
                              hipStream_t stream) {
    const float* item = (const float*)d_in[0];
    const float* seqL = (const float*)d_in[1];
    const float* seqS = (const float*)d_in[2];
    const int*   indL = (const int*)d_in[3];
    const int*   indS = (const int*)d_in[4];
    const float* embL = (const float*)d_in[5];
    const float* embS = (const float*)d_in[6];

    const int B   = in_sizes[0] / 64;
    const int SL  = in_sizes[1] / (B * 64);
    const int SS  = in_sizes[2] / (B * 64);
    const int nbL = in_sizes[5] / 8;   // 22
    const int nbS = in_sizes[6] / 8;   // 42
    const int nchL = SL / CHUNK;       // 8
    const int nchS = SS / CHUNK;       // 2
    const int totalChunks = B * nchL + B * nchS;       // 10240
    const int rounds = (totalChunks + NBLK - 1) / NBLK; // 5

    float* out  = (float*)d_out;
    float* cosL = out;
    float* cosS = cosL + (size_t)B * SL;
    float* stL  = cosS + (size_t)B * SS;
    float* stS  = stL  + (size_t)B * nbL * 8;

    int* histG = (int*)d_ws;                       // [2B][64] ints
    (void)hipMemsetAsync(histG, 0, (size_t)2 * B * 64 * sizeof(int), stream);

    dim3 grid1(NBLK), block1(256);
    hipLaunchKernelGGL(cosine_chunk_kernel, grid1, block1, 0, stream,
                       item, seqL, indL, seqS, indS,
                       cosL, cosS, histG, B, SL, SS, nbL, nbS,
                       nchL, totalChunks, rounds);

    dim3 grid2(2 * B), block2(64);
    hipLaunchKernelGGL(simtier_epilogue_kernel, grid2, block2, 0, stream,
                       histG, embL, embS, stL, stS, B, nbL, nbS);
}

// Round 10
// 77.706 us; speedup vs baseline: 1.9150x; 1.9150x over previous
//
#include <hip/hip_runtime.h>
#include <math.h>

#define CHUNK 512   // rows per block; SL=2048 -> 4 chunks, SS=512 -> 1 chunk

// Uniform-work kernel. 4 lanes per row (4 x float4 each), 2 rows per thread
// per iteration. KEY: ~50% of rows have indicator==0 -> output is the
// constant -2.0 and no histogram contribution. For those rows we skip the
// 256B seq load entirely (exec-masked at 4-lane granularity), halving HBM
// read traffic. Indicators are hoisted to registers at chunk start.
__global__ __launch_bounds__(256) void cosine_chunk_kernel(
    const float* __restrict__ item,
    const float* __restrict__ seqL, const int* __restrict__ indL,
    const float* __restrict__ seqS, const int* __restrict__ indS,
    float* __restrict__ cosL, float* __restrict__ cosS,
    int* __restrict__ histG,
    int B, int SL, int SS, int nbL, int nbS, int nchL)
{
    const int blk = (int)blockIdx.x;
    const bool isLong = blk < B * nchL;
    const int b     = isLong ? (blk / nchL) : (blk - B * nchL);
    const int chunk = isLong ? (blk % nchL) : 0;
    const int S     = isLong ? SL : SS;
    const int nb    = isLong ? nbL : nbS;
    const int bias  = (nb - 2) / 2;          // 22 -> 10, 42 -> 20
    const float scale = (float)bias;         // exactly 1/eps
    const int job   = isLong ? b : B + b;    // global hist row
    const float* __restrict__ seq = isLong ? seqL : seqS;
    const int*   __restrict__ ind = isLong ? indL : indS;
    float* __restrict__ cosOut = isLong ? cosL : cosS;

    const int tid = threadIdx.x;
    __shared__ float item_n[64];
    __shared__ int   hist[64];

    if (tid < 64) {
        float v = item[(size_t)b * 64 + tid];
        float sq = v * v;
        #pragma unroll
        for (int off = 32; off >= 1; off >>= 1)
            sq += __shfl_xor(sq, off, 64);
        item_n[tid] = v * (1.0f / (sqrtf(sq) + 1e-8f));
        hist[tid] = 0;
    }
    __syncthreads();

    const int lane4 = tid & 3;               // float4 slot phase within row
    const int rowId = tid >> 2;              // 0..63: row offset in iter
    const float4* __restrict__ item4 = reinterpret_cast<const float4*>(item_n);
    const float4 i0 = item4[0 * 4 + lane4];
    const float4 i1 = item4[1 * 4 + lane4];
    const float4 i2 = item4[2 * 4 + lane4];
    const float4 i3 = item4[3 * 4 + lane4];

    const float4* __restrict__ seqb = reinterpret_cast<const float4*>(seq) + (size_t)b * S * 16;
    const int*    __restrict__ indb = ind    + (size_t)b * S;
    float*        __restrict__ cosb = cosOut + (size_t)b * S;

    const int rowBeg = chunk * CHUNK;        // CHUNK divisible by 128
    #define NIT (CHUNK / 128)                // 4 iterations

    // Hoist all indicator loads for this thread's 8 rows: one latency hit,
    // all in flight together, consumed from registers in the loop.
    int ivs[2 * NIT];
    #pragma unroll
    for (int it = 0; it < NIT; ++it) {
        ivs[2 * it + 0] = indb[rowBeg + it * 128 + rowId];
        ivs[2 * it + 1] = indb[rowBeg + it * 128 + rowId + 64];
    }

    #pragma unroll
    for (int it = 0; it < NIT; ++it) {
        const int r0 = rowBeg + it * 128 + rowId;
        const int r1 = r0 + 64;
        const bool ok0 = ivs[2 * it + 0] > 0;
        const bool ok1 = ivs[2 * it + 1] > 0;

        const float4* P = &seqb[(size_t)r0 * 16 + lane4];
        float4 a0{}, a1{}, a2{}, a3{}, b0{}, b1{}, b2{}, b3{};
        if (ok0) { a0 = P[0];    a1 = P[4];    a2 = P[8];    a3 = P[12];   }
        if (ok1) { b0 = P[1024]; b1 = P[1028]; b2 = P[1032]; b3 = P[1036]; }

        float dot0 = i0.x*a0.x + i0.y*a0.y + i0.z*a0.z + i0.w*a0.w
                   + i1.x*a1.x + i1.y*a1.y + i1.z*a1.z + i1.w*a1.w
                   + i2.x*a2.x + i2.y*a2.y + i2.z*a2.z + i2.w*a2.w
                   + i3.x*a3.x + i3.y*a3.y + i3.z*a3.z + i3.w*a3.w;
        float sq0  = a0.x*a0.x + a0.y*a0.y + a0.z*a0.z + a0.w*a0.w
                   + a1.x*a1.x + a1.y*a1.y + a1.z*a1.z + a1.w*a1.w
                   + a2.x*a2.x + a2.y*a2.y + a2.z*a2.z + a2.w*a2.w
                   + a3.x*a3.x + a3.y*a3.y + a3.z*a3.z + a3.w*a3.w;
        float dot1 = i0.x*b0.x + i0.y*b0.y + i0.z*b0.z + i0.w*b0.w
                   + i1.x*b1.x + i1.y*b1.y + i1.z*b1.z + i1.w*b1.w
                   + i2.x*b2.x + i2.y*b2.y + i2.z*b2.z + i2.w*b2.w
                   + i3.x*b3.x + i3.y*b3.y + i3.z*b3.z + i3.w*b3.w;
        float sq1  = b0.x*b0.x + b0.y*b0.y + b0.z*b0.z + b0.w*b0.w
                   + b1.x*b1.x + b1.y*b1.y + b1.z*b1.z + b1.w*b1.w
                   + b2.x*b2.x + b2.y*b2.y + b2.z*b2.z + b2.w*b2.w
                   + b3.x*b3.x + b3.y*b3.y + b3.z*b3.z + b3.w*b3.w;

        #pragma unroll
        for (int off = 1; off <= 2; off <<= 1) {
            dot0 += __shfl_xor(dot0, off, 64);
            sq0  += __shfl_xor(sq0,  off, 64);
            dot1 += __shfl_xor(dot1, off, 64);
            sq1  += __shfl_xor(sq1,  off, 64);
        }

        if (lane4 == 0) {
            float cos0 = ok0 ? dot0 / (sqrtf(sq0) + 1e-8f) : -2.0f;
            cosb[r0] = cos0;
            const int id0 = (int)ceilf(cos0 * scale) + bias;
            if (id0 >= 0 && id0 < nb) atomicAdd(&hist[id0], 1);

            float cos1 = ok1 ? dot1 / (sqrtf(sq1) + 1e-8f) : -2.0f;
            cosb[r1] = cos1;
            const int id1 = (int)ceilf(cos1 * scale) + bias;
            if (id1 >= 0 && id1 < nb) atomicAdd(&hist[id1], 1);
        }
    }
    __syncthreads();

    // Merge block-local histogram into the global per-job histogram.
    if (tid < 64) {
        const int c = hist[tid];
        if (c > 0) atomicAdd(&histG[(size_t)job * 64 + tid], c);
    }
}

// Tiny epilogue: st[b, id*8+j] = log(count+1) * emb[id*8+j]
__global__ __launch_bounds__(64) void simtier_epilogue_kernel(
    const int* __restrict__ histG,
    const float* __restrict__ embL, const float* __restrict__ embS,
    float* __restrict__ stL, float* __restrict__ stS,
    int B, int nbL, int nbS)
{
    const int j = (int)blockIdx.x;           // 0..2B-1
    const bool isLong = j < B;
    const int b  = isLong ? j : j - B;
    const int nb = isLong ? nbL : nbS;
    const float* __restrict__ emb = isLong ? embL : embS;
    float* __restrict__ st = isLong ? stL : stS;
    const int* __restrict__ h = histG + (size_t)j * 64;

    const int nout = nb * 8;
    for (int t = threadIdx.x; t < nout; t += 64) {
        const float c = (float)h[t >> 3];
        st[(size_t)b * nout + t] = logf(c + 1.0f) * emb[t];
    }
}

extern "C" void kernel_launch(void* const* d_in, const int* in_sizes, int n_in,
                              void* d_out, int out_size, void* d_ws, size_t ws_size,
                              hipStream_t stream) {
    const float* item = (const float*)d_in[0];
    const float* seqL = (const float*)d_in[1];
    const float* seqS = (const float*)d_in[2];
    const int*   indL = (const int*)d_in[3];
    const int*   indS = (const int*)d_in[4];
    const float* embL = (const float*)d_in[5];
    const float* embS = (const float*)d_in[6];

    const int B   = in_sizes[0] / 64;
    const int SL  = in_sizes[1] / (B * 64);
    const int SS  = in_sizes[2] / (B * 64);
    const int nbL = in_sizes[5] / 8;   // 22
    const int nbS = in_sizes[6] / 8;   // 42
    const int nchL = SL / CHUNK;       // 4
    const int nchS = SS / CHUNK;       // 1

    float* out  = (float*)d_out;
    float* cosL = out;
    float* cosS = cosL + (size_t)B * SL;
    float* stL  = cosS + (size_t)B * SS;
    float* stS  = stL  + (size_t)B * nbL * 8;

    int* histG = (int*)d_ws;                       // [2B][64] ints
    (void)hipMemsetAsync(histG, 0, (size_t)2 * B * 64 * sizeof(int), stream);

    dim3 grid1(B * nchL + B * nchS), block1(256);
    hipLaunchKernelGGL(cosine_chunk_kernel, grid1, block1, 0, stream,
                       item, seqL, indL, seqS, indS,
                       cosL, cosS, histG, B, SL, SS, nbL, nbS, nchL);

    dim3 grid2(2 * B), block2(64);
    hipLaunchKernelGGL(simtier_epilogue_kernel, grid2, block2, 0, stream,
                       histG, embL, embS, stL, stS, B, nbL, nbS);
}